// Round 5
// baseline (413.416 us; speedup 1.0000x reference)
//
#include <hip/hip_runtime.h>
#include <stdint.h>

typedef __attribute__((ext_vector_type(8))) short s8v;     // 8 x bf16 bits
typedef __attribute__((ext_vector_type(4))) float f32x4;

#define HEADS 16
#define DH    64
#define SEG   512
#define PM    16
#define NKV   528      // PM + SEG
#define KVP   576      // padded keys
#define DIM   1024
#define NQKV  3072
#define MTOT  16384    // 2*8192

__device__ __forceinline__ unsigned short f2bf(float f) {
  union { float f; unsigned u; } v; v.f = f;
  unsigned r = v.u + 0x7fffu + ((v.u >> 16) & 1u);
  return (unsigned short)(r >> 16);
}

__device__ __forceinline__ void mfma_bf16(f32x4& c, s8v a, s8v b) {
  asm("v_mfma_f32_16x16x32_bf16 %0, %1, %2, %0" : "+v"(c) : "v"(a), "v"(b));
}

__device__ __forceinline__ void gload_lds16(const unsigned short* g, unsigned short* l) {
  __builtin_amdgcn_global_load_lds(
      (const __attribute__((address_space(1))) unsigned int*)g,
      (__attribute__((address_space(3))) unsigned int*)l, 16, 0, 0);
}

// ---------------- prep kernels ----------------
__global__ void prep_rope(float* costab, float* sintab) {
  int idx = blockIdx.x * 256 + threadIdx.x;   // 8192*32
  int n = idx >> 5, p = idx & 31;
  double inv = pow(10000.0, -(double)p / 32.0);
  double ang = (double)n * inv;
  costab[idx] = (float)cos(ang);
  sintab[idx] = (float)sin(ang);
}

__global__ void transpose_w(const float* in, unsigned short* out, int K, int N) {
  // in [K][N] f32 -> out [N][K] bf16
  __shared__ float tile[32][33];
  int n0 = blockIdx.x * 32, k0 = blockIdx.y * 32;
  int tx = threadIdx.x, ty = threadIdx.y;   // (32,8)
  for (int i = ty; i < 32; i += 8) tile[i][tx] = in[(size_t)(k0 + i) * N + n0 + tx];
  __syncthreads();
  for (int i = ty; i < 32; i += 8) out[(size_t)(n0 + i) * K + k0 + tx] = f2bf(tile[tx][i]);
}

__global__ void prep_pm(const float* pm_k, const float* pm_v,
                        unsigned short* k_ws, unsigned short* v_ws) {
  int idx = blockIdx.x * 256 + threadIdx.x;   // 32*16*16*64
  int d = idx & 63, t = (idx >> 6) & 15, h = (idx >> 10) & 15, bw = idx >> 14;
  int sh = bw * 16 + h;
  k_ws[((size_t)sh * KVP + t) * 64 + d] = f2bf(pm_k[((h * 16 + t) << 6) + d]);
  v_ws[((size_t)sh * 64 + d) * KVP + t] = f2bf(pm_v[((h * 16 + t) << 6) + d]);
}

__global__ void clear_vpad(unsigned short* v_ws) {
  int idx = blockIdx.x * 256 + threadIdx.x;   // 512*64*48
  int t = idx % 48; int rest = idx / 48; int d = rest & 63; int sh = rest >> 6;
  v_ws[((size_t)sh * 64 + d) * KVP + NKV + t] = 0;
}

// ---------------- rmsnorm ----------------
__global__ __launch_bounds__(256) void rmsnorm_k(const float* x, const float* w,
                                                 unsigned short* xn) {
  int row = blockIdx.x, tid = threadIdx.x;
  float4 v = ((const float4*)(x + (size_t)row * DIM))[tid];
  float ss = v.x * v.x + v.y * v.y + v.z * v.z + v.w * v.w;
  #pragma unroll
  for (int o = 32; o > 0; o >>= 1) ss += __shfl_xor(ss, o);
  __shared__ float red[4];
  if ((tid & 63) == 0) red[tid >> 6] = ss;
  __syncthreads();
  ss = red[0] + red[1] + red[2] + red[3];
  float rs = rsqrtf(ss * (1.0f / 1024.0f) + 1e-6f);
  float4 wv = ((const float4*)w)[tid];
  ushort4 o;
  o.x = f2bf(v.x * rs * wv.x); o.y = f2bf(v.y * rs * wv.y);
  o.z = f2bf(v.z * rs * wv.z); o.w = f2bf(v.w * rs * wv.w);
  ((ushort4*)(xn + (size_t)row * DIM))[tid] = o;
}

// ---------------- GEMM 1: qkv = xn @ WqkvT, fused rope + scatter ----------------
__global__ __launch_bounds__(256) void gemm_qkv(const unsigned short* A, const unsigned short* Bt,
                                                const float* costab, const float* sintab,
                                                unsigned short* q_ws, unsigned short* k_ws,
                                                unsigned short* v_ws) {
  __shared__ unsigned short Als[4096];
  __shared__ unsigned short Bls[4096];
  int tid = threadIdx.x, lane = tid & 63, wid = tid >> 6;
  int n0 = blockIdx.x * 128, m0 = blockIdx.y * 128;
  f32x4 acc[4][4] = {};
  int c2 = tid + 256;
  const unsigned short* ga1 = A + (size_t)(m0 + (tid >> 2)) * DIM + (tid & 3) * 8;
  const unsigned short* ga2 = A + (size_t)(m0 + (c2 >> 2)) * DIM + (c2 & 3) * 8;
  const unsigned short* gb1 = Bt + (size_t)(n0 + (tid >> 2)) * DIM + (tid & 3) * 8;
  const unsigned short* gb2 = Bt + (size_t)(n0 + (c2 >> 2)) * DIM + (c2 & 3) * 8;
  unsigned short* lA1 = &Als[wid * 512];
  unsigned short* lA2 = &Als[2048 + wid * 512];
  unsigned short* lB1 = &Bls[wid * 512];
  unsigned short* lB2 = &Bls[2048 + wid * 512];
  int mb = (wid >> 1) * 64, nb = (wid & 1) * 64;
  int lr = lane & 15, lg = lane >> 4;

  for (int kt = 0; kt < DIM; kt += 32) {
    gload_lds16(ga1 + kt, lA1);
    gload_lds16(ga2 + kt, lA2);
    gload_lds16(gb1 + kt, lB1);
    gload_lds16(gb2 + kt, lB2);
    __syncthreads();
    s8v a[4], b[4];
    #pragma unroll
    for (int i = 0; i < 4; i++) a[i] = *(const s8v*)&Als[(mb + i * 16 + lr) * 32 + lg * 8];
    #pragma unroll
    for (int i = 0; i < 4; i++) b[i] = *(const s8v*)&Bls[(nb + i * 16 + lr) * 32 + lg * 8];
    #pragma unroll
    for (int i = 0; i < 4; i++)
      #pragma unroll
      for (int j = 0; j < 4; j++)
        mfma_bf16(acc[i][j], a[i], b[j]);
    __syncthreads();
  }

  // epilogue: rope on q/k, scatter into attention layouts.
  #pragma unroll
  for (int i = 0; i < 4; i++) {
    #pragma unroll
    for (int j = 0; j < 4; j++) {
      int colbase = n0 + nb + j * 16;          // wave-uniform
      int type = colbase >> 10;                // 0=q 1=k 2=v
      int hh = (colbase & 1023) >> 6;
      int d0 = colbase & 63;
      int d = d0 + lr;
      int rowt = m0 + mb + i * 16;             // tile row base (no lg)
      int rowb = rowt + lg * 4;
      f32x4 v = acc[i][j];
      if (type < 2) {
        int p = d >> 1;
        float vr[4];
        #pragma unroll
        for (int r = 0; r < 4; r++) {
          float partner = __shfl_xor(v[r], 1);
          int npos = (rowb + r) & 8191;
          float cth = costab[npos * 32 + p];
          float sth = sintab[npos * 32 + p];
          vr[r] = (d & 1) ? (v[r] * cth + partner * sth)
                          : (v[r] * cth - partner * sth);
        }
        #pragma unroll
        for (int r = 0; r < 4; r++) {
          int m = rowb + r;
          int bw = m >> 9, pos = m & 511;
          int sh = bw * 16 + hh;
          unsigned short bits = f2bf(vr[r]);
          if (type == 0) q_ws[((size_t)sh * SEG + pos) * 64 + d] = bits;
          else           k_ws[((size_t)sh * KVP + PM + pos) * 64 + d] = bits;
        }
      } else {
        // V: transpose 16x16 tile through wave-private LDS so global stores
        // are contiguous along pos. Als is free after the last __syncthreads.
        unsigned short* T = &Als[wid * 1024];
        #pragma unroll
        for (int r = 0; r < 4; r++)
          T[lr * 17 + lg * 4 + r] = f2bf(v[r]);        // T[d_local][pos_local]
        int sh = (rowt >> 9) * 16 + hh;
        int pos0 = rowt & 511;
        #pragma unroll
        for (int r2 = 0; r2 < 4; r2++) {
          int dloc = lg * 4 + r2;
          unsigned short bits = T[dloc * 17 + lr];
          v_ws[((size_t)sh * 64 + d0 + dloc) * KVP + PM + pos0 + lr] = bits;
        }
      }
    }
  }
}

// ---------------- attention (R2-proven structure, K/V destaged) ----------------
// Identical arithmetic/layout to the R2 version that passed. Only changes:
//  - K/V fragments load directly from global (byte-identical to the staged
//    LDS reads they replace; KV is L2-resident, staging was a pure copy)
//  - the staging barrier is gone; the loop-end __syncthreads() is kept so
//    the P round-trip retains every ordering guarantee it had in R2
//  - s_setprio(1) around MFMA clusters (T5)
__global__ __launch_bounds__(256) void attn_k(const unsigned short* q_ws,
                                              const unsigned short* k_ws,
                                              const unsigned short* v_ws,
                                              unsigned short* attn_out) {
  __shared__ unsigned short Pls[128 * 72];  // per-wave 32 rows
  int bid = blockIdx.x;
  int qt = bid & 3, h = (bid >> 2) & 15, s = bid >> 6;
  int sh = s * 16 + h;
  int tid = threadIdx.x, lane = tid & 63, wid = tid >> 6;
  int lr = lane & 15, lg = lane >> 4;
  int qrow0 = qt * 128 + wid * 32;

  s8v qf[2][2];
  #pragma unroll
  for (int mi = 0; mi < 2; mi++)
    #pragma unroll
    for (int kk = 0; kk < 2; kk++) {
      size_t row = (size_t)sh * SEG + qrow0 + mi * 16 + lr;
      qf[mi][kk] = *(const s8v*)&q_ws[row * 64 + kk * 32 + lg * 8];
    }

  f32x4 O[2][4] = {};
  float mrun[2][4], lrun[2][4];
  #pragma unroll
  for (int mi = 0; mi < 2; mi++)
    #pragma unroll
    for (int r = 0; r < 4; r++) { mrun[mi][r] = -1e30f; lrun[mi][r] = 0.0f; }

  const unsigned short* kbase = k_ws + (size_t)sh * KVP * 64;
  const unsigned short* vbase = v_ws + (size_t)sh * 64 * KVP;
  int nchunk = 2 * qt + 3;

  for (int cc = 0; cc < nchunk; ++cc) {
    int kc0 = cc * 64;
    // K frags (B-operand), bytes identical to R2's Kls[(ni*16+lr)*72 + kk*32+lg*8]
    s8v kf[4][2];
    #pragma unroll
    for (int ni = 0; ni < 4; ni++)
      #pragma unroll
      for (int kk = 0; kk < 2; kk++)
        kf[ni][kk] = *(const s8v*)&kbase[(size_t)(kc0 + ni * 16 + lr) * 64 + kk * 32 + lg * 8];
    // V frags (B-operand), bytes identical to R2's Vls[(oi*16+lr)*72 + kk*32+lg*8]
    s8v vf[4][2];
    #pragma unroll
    for (int oi = 0; oi < 4; oi++)
      #pragma unroll
      for (int kk = 0; kk < 2; kk++)
        vf[oi][kk] = *(const s8v*)&vbase[(size_t)(oi * 16 + lr) * KVP + kc0 + kk * 32 + lg * 8];

    f32x4 S[2][4] = {};
    __builtin_amdgcn_s_setprio(1);
    #pragma unroll
    for (int kk = 0; kk < 2; kk++)
      #pragma unroll
      for (int ni = 0; ni < 4; ni++)
        #pragma unroll
        for (int mi = 0; mi < 2; mi++)
          mfma_bf16(S[mi][ni], qf[mi][kk], kf[ni][kk]);
    __builtin_amdgcn_s_setprio(0);

    #pragma unroll
    for (int mi = 0; mi < 2; mi++) {
      #pragma unroll
      for (int r = 0; r < 4; r++) {
        int qpos = qrow0 + mi * 16 + lg * 4 + r;
        float mx = -1e30f;
        float sv[4];
        #pragma unroll
        for (int ni = 0; ni < 4; ni++) {
          int col = kc0 + ni * 16 + lr;
          float xv = S[mi][ni][r] * 0.125f;
          bool ok = (col < PM) || ((col - PM) <= qpos);
          xv = ok ? xv : -1e30f;
          sv[ni] = xv;
          mx = fmaxf(mx, xv);
        }
        #pragma unroll
        for (int o = 1; o < 16; o <<= 1) mx = fmaxf(mx, __shfl_xor(mx, o));
        float mnew = fmaxf(mrun[mi][r], mx);
        float scl = __expf(mrun[mi][r] - mnew);
        mrun[mi][r] = mnew;
        float rs = 0.0f;
        #pragma unroll
        for (int ni = 0; ni < 4; ni++) {
          float p = __expf(sv[ni] - mnew);
          S[mi][ni][r] = p;
          rs += p;
        }
        #pragma unroll
        for (int o = 1; o < 16; o <<= 1) rs += __shfl_xor(rs, o);
        lrun[mi][r] = lrun[mi][r] * scl + rs;
        #pragma unroll
        for (int oi = 0; oi < 4; oi++) O[mi][oi][r] *= scl;
      }
    }

    // P -> LDS (per-wave private region; exact R2 pattern: scalar ushort
    // writes, s8v reads, no barrier between write and read — proven in R2)
    #pragma unroll
    for (int mi = 0; mi < 2; mi++)
      #pragma unroll
      for (int ni = 0; ni < 4; ni++)
        #pragma unroll
        for (int r = 0; r < 4; r++)
          Pls[(wid * 32 + mi * 16 + lg * 4 + r) * 72 + ni * 16 + lr] = f2bf(S[mi][ni][r]);

    __builtin_amdgcn_s_setprio(1);
    #pragma unroll
    for (int kk = 0; kk < 2; kk++) {
      s8v pa[2];
      #pragma unroll
      for (int mi = 0; mi < 2; mi++)
        pa[mi] = *(const s8v*)&Pls[(wid * 32 + mi * 16 + lr) * 72 + kk * 32 + lg * 8];
      #pragma unroll
      for (int oi = 0; oi < 4; oi++)
        #pragma unroll
        for (int mi = 0; mi < 2; mi++)
          mfma_bf16(O[mi][oi], pa[mi], vf[oi][kk]);
    }
    __builtin_amdgcn_s_setprio(0);
    // loop-end barrier kept from R2: orders this chunk's P-reads before the
    // next chunk's P-writes (same guarantee set R2 ran with)
    __syncthreads();
  }

  int mbase = (s >> 4) * 8192 + (s & 15) * 512;
  #pragma unroll
  for (int mi = 0; mi < 2; mi++)
    #pragma unroll
    for (int r = 0; r < 4; r++) {
      float inv = 1.0f / lrun[mi][r];
      int qpos = qrow0 + mi * 16 + lg * 4 + r;
      size_t m = (size_t)mbase + qpos;
      #pragma unroll
      for (int oi = 0; oi < 4; oi++)
        attn_out[m * DIM + h * 64 + oi * 16 + lr] = f2bf(O[mi][oi][r] * inv);
    }
}

// ---------------- GEMM 2: out = attn @ WoutT + b ----------------
__global__ __launch_bounds__(256) void gemm_out(const unsigned short* A, const unsigned short* Bt,
                                                const float* bias, float* out) {
  __shared__ unsigned short Als[4096];
  __shared__ unsigned short Bls[4096];
  int tid = threadIdx.x, lane = tid & 63, wid = tid >> 6;
  int n0 = blockIdx.x * 128, m0 = blockIdx.y * 128;
  f32x4 acc[4][4] = {};
  int c2 = tid + 256;
  const unsigned short* ga1 = A + (size_t)(m0 + (tid >> 2)) * DIM + (tid & 3) * 8;
  const unsigned short* ga2 = A + (size_t)(m0 + (c2 >> 2)) * DIM + (c2 & 3) * 8;
  const unsigned short* gb1 = Bt + (size_t)(n0 + (tid >> 2)) * DIM + (tid & 3) * 8;
  const unsigned short* gb2 = Bt + (size_t)(n0 + (c2 >> 2)) * DIM + (c2 & 3) * 8;
  unsigned short* lA1 = &Als[wid * 512];
  unsigned short* lA2 = &Als[2048 + wid * 512];
  unsigned short* lB1 = &Bls[wid * 512];
  unsigned short* lB2 = &Bls[2048 + wid * 512];
  int mb = (wid >> 1) * 64, nb = (wid & 1) * 64;
  int lr = lane & 15, lg = lane >> 4;

  for (int kt = 0; kt < DIM; kt += 32) {
    gload_lds16(ga1 + kt, lA1);
    gload_lds16(ga2 + kt, lA2);
    gload_lds16(gb1 + kt, lB1);
    gload_lds16(gb2 + kt, lB2);
    __syncthreads();
    s8v a[4], b[4];
    #pragma unroll
    for (int i = 0; i < 4; i++) a[i] = *(const s8v*)&Als[(mb + i * 16 + lr) * 32 + lg * 8];
    #pragma unroll
    for (int i = 0; i < 4; i++) b[i] = *(const s8v*)&Bls[(nb + i * 16 + lr) * 32 + lg * 8];
    #pragma unroll
    for (int i = 0; i < 4; i++)
      #pragma unroll
      for (int j = 0; j < 4; j++)
        mfma_bf16(acc[i][j], a[i], b[j]);
    __syncthreads();
  }

  #pragma unroll
  for (int i = 0; i < 4; i++)
    #pragma unroll
    for (int j = 0; j < 4; j++) {
      int c = n0 + nb + j * 16 + lr;
      float bv = bias[c];
      #pragma unroll
      for (int r = 0; r < 4; r++) {
        int m = m0 + mb + i * 16 + lg * 4 + r;
        out[(size_t)m * DIM + c] = acc[i][j][r] + bv;
      }
    }
}

// ---------------- launch ----------------
extern "C" void kernel_launch(void* const* d_in, const int* in_sizes, int n_in,
                              void* d_out, int out_size, void* d_ws, size_t ws_size,
                              hipStream_t stream) {
  (void)in_sizes; (void)n_in; (void)out_size; (void)ws_size;
  const float* seq    = (const float*)d_in[0];
  const float* norm_w = (const float*)d_in[1];
  const float* w_qkv  = (const float*)d_in[2];
  const float* pm_k   = (const float*)d_in[3];
  const float* pm_v   = (const float*)d_in[4];
  const float* w_out  = (const float*)d_in[5];
  const float* b_out  = (const float*)d_in[6];
  float* out = (float*)d_out;

  char* ws = (char*)d_ws;
  unsigned short* xn    = (unsigned short*)(ws);              // 33,554,432 B
  unsigned short* wqkvT = (unsigned short*)(ws + 33554432);   //  6,291,456
  unsigned short* woutT = (unsigned short*)(ws + 39845888);   //  2,097,152
  float* costab         = (float*)(ws + 41943040);            //  1,048,576
  float* sintab         = (float*)(ws + 42991616);            //  1,048,576
  unsigned short* q_ws  = (unsigned short*)(ws + 44040192);   // 33,554,432
  unsigned short* k_ws  = (unsigned short*)(ws + 77594624);   // 37,748,736
  unsigned short* v_ws  = (unsigned short*)(ws + 115343360);  // 37,748,736
  unsigned short* attno = (unsigned short*)(ws + 153092096);  // 33,554,432 (end 186,646,528)

  prep_rope<<<1024, 256, 0, stream>>>(costab, sintab);
  transpose_w<<<dim3(96, 32), dim3(32, 8), 0, stream>>>(w_qkv, wqkvT, 1024, 3072);
  transpose_w<<<dim3(32, 32), dim3(32, 8), 0, stream>>>(w_out, woutT, 1024, 1024);
  prep_pm<<<2048, 256, 0, stream>>>(pm_k, pm_v, k_ws, v_ws);
  clear_vpad<<<6144, 256, 0, stream>>>(v_ws);
  rmsnorm_k<<<16384, 256, 0, stream>>>(seq, norm_w, xn);
  gemm_qkv<<<dim3(24, 128), 256, 0, stream>>>(xn, wqkvT, costab, sintab, q_ws, k_ws, v_ws);
  attn_k<<<2048, 256, 0, stream>>>(q_ws, k_ws, v_ws, attno);
  gemm_out<<<dim3(8, 128), 256, 0, stream>>>(attno, woutT, b_out, out);
}

// Round 6
// 337.184 us; speedup vs baseline: 1.2261x; 1.2261x over previous
//
#include <hip/hip_runtime.h>
#include <stdint.h>

typedef __attribute__((ext_vector_type(8))) short s8v;     // 8 x bf16 bits
typedef __attribute__((ext_vector_type(4))) float f32x4;

#define HEADS 16
#define DH    64
#define SEG   512
#define PM    16
#define NKV   528      // PM + SEG
#define DIM   1024

// frag-major layouts (elements, per sh = seg*16+head):
//  Q: 512x64  -> off = ((rb*2+kk)*64 + lg*16 + lr)*8 + j   rb=row>>4, lr=row&15, kk=d>>5, lg=(d>>3)&3, j=d&7   (32768 elems)
//  K: 576x64  -> off = ch*4096 + ((ni*2+kk)*64 + lg*16 + lr)*8 + j   ch=key>>6, ni=(key>>4)&3, lr=key&15       (36864 elems)
//  V: 576x64  -> off = ch*4096 + ((kk*4+oi)*64 + lg*16 + lr)*8 + j   kk=(key>>5)&1, lg=(key>>3)&3, j=key&7, oi=d>>4, lr=d&15

__device__ __forceinline__ unsigned short f2bf(float f) {
  union { float f; unsigned u; } v; v.f = f;
  unsigned r = v.u + 0x7fffu + ((v.u >> 16) & 1u);
  return (unsigned short)(r >> 16);
}

__device__ __forceinline__ void mfma_bf16(f32x4& c, s8v a, s8v b) {
  asm("v_mfma_f32_16x16x32_bf16 %0, %1, %2, %0" : "+v"(c) : "v"(a), "v"(b));
}

__device__ __forceinline__ void gload_lds16(const unsigned short* g, unsigned short* l) {
  __builtin_amdgcn_global_load_lds(
      (const __attribute__((address_space(1))) unsigned int*)g,
      (__attribute__((address_space(3))) unsigned int*)l, 16, 0, 0);
}

// ---------------- prep kernels ----------------
__global__ void prep_rope(float* costab, float* sintab) {
  int idx = blockIdx.x * 256 + threadIdx.x;   // 8192*32
  int n = idx >> 5, p = idx & 31;
  double inv = pow(10000.0, -(double)p / 32.0);
  double ang = (double)n * inv;
  costab[idx] = (float)cos(ang);
  sintab[idx] = (float)sin(ang);
}

__global__ void transpose_w(const float* in, unsigned short* out, int K, int N) {
  // in [K][N] f32 -> out [N][K] bf16
  __shared__ float tile[32][33];
  int n0 = blockIdx.x * 32, k0 = blockIdx.y * 32;
  int tx = threadIdx.x, ty = threadIdx.y;   // (32,8)
  for (int i = ty; i < 32; i += 8) tile[i][tx] = in[(size_t)(k0 + i) * N + n0 + tx];
  __syncthreads();
  for (int i = ty; i < 32; i += 8) out[(size_t)(n0 + i) * K + k0 + tx] = f2bf(tile[tx][i]);
}

__global__ void prep_pm(const float* pm_k, const float* pm_v,
                        unsigned short* k_ws, unsigned short* v_ws) {
  int idx = blockIdx.x * 256 + threadIdx.x;   // 32*16*16*64
  int d = idx & 63, t = (idx >> 6) & 15, h = (idx >> 10) & 15, bw = idx >> 14;
  int sh = bw * 16 + h;
  float kv = pm_k[((h * 16 + t) << 6) + d];
  float vv = pm_v[((h * 16 + t) << 6) + d];
  // K: key=t (ch=0, ni=0, lr=t); kk=d>>5, lg=(d>>3)&3, j=d&7
  k_ws[(size_t)sh * 36864 + (((d >> 5) * 64) + ((d >> 3) & 3) * 16 + t) * 8 + (d & 7)] = f2bf(kv);
  // V: key=t (ch=0, kk=0, lg=t>>3, j=t&7); oi=d>>4, lr=d&15
  v_ws[(size_t)sh * 36864 + (((d >> 4) * 64) + (t >> 3) * 16 + (d & 15)) * 8 + (t & 7)] = f2bf(vv);
}

__global__ void clear_vpad(unsigned short* v_ws) {
  int idx = blockIdx.x * 256 + threadIdx.x;   // 512*64*48
  int t = idx % 48; int rest = idx / 48; int d = rest & 63; int sh = rest >> 6;
  int key = NKV + t;                           // 528..575, ch=8
  int kk = (key >> 5) & 1, lg = (key >> 3) & 3, j = key & 7;
  v_ws[(size_t)sh * 36864 + 8 * 4096 + ((kk * 4 + (d >> 4)) * 64 + lg * 16 + (d & 15)) * 8 + j] = 0;
}

// ---------------- rmsnorm ----------------
__global__ __launch_bounds__(256) void rmsnorm_k(const float* x, const float* w,
                                                 unsigned short* xn) {
  int row = blockIdx.x, tid = threadIdx.x;
  float4 v = ((const float4*)(x + (size_t)row * DIM))[tid];
  float ss = v.x * v.x + v.y * v.y + v.z * v.z + v.w * v.w;
  #pragma unroll
  for (int o = 32; o > 0; o >>= 1) ss += __shfl_xor(ss, o);
  __shared__ float red[4];
  if ((tid & 63) == 0) red[tid >> 6] = ss;
  __syncthreads();
  ss = red[0] + red[1] + red[2] + red[3];
  float rs = rsqrtf(ss * (1.0f / 1024.0f) + 1e-6f);
  float4 wv = ((const float4*)w)[tid];
  ushort4 o;
  o.x = f2bf(v.x * rs * wv.x); o.y = f2bf(v.y * rs * wv.y);
  o.z = f2bf(v.z * rs * wv.z); o.w = f2bf(v.w * rs * wv.w);
  ((ushort4*)(xn + (size_t)row * DIM))[tid] = o;
}

// ---------------- GEMM 1: qkv = xn @ WqkvT, fused rope + frag-major scatter ----------------
__global__ __launch_bounds__(256) void gemm_qkv(const unsigned short* A, const unsigned short* Bt,
                                                const float* costab, const float* sintab,
                                                unsigned short* q_ws, unsigned short* k_ws,
                                                unsigned short* v_ws) {
  __shared__ unsigned short Als[4096];
  __shared__ unsigned short Bls[4096];
  int tid = threadIdx.x, lane = tid & 63, wid = tid >> 6;
  int n0 = blockIdx.x * 128, m0 = blockIdx.y * 128;
  f32x4 acc[4][4] = {};
  int c2 = tid + 256;
  const unsigned short* ga1 = A + (size_t)(m0 + (tid >> 2)) * DIM + (tid & 3) * 8;
  const unsigned short* ga2 = A + (size_t)(m0 + (c2 >> 2)) * DIM + (c2 & 3) * 8;
  const unsigned short* gb1 = Bt + (size_t)(n0 + (tid >> 2)) * DIM + (tid & 3) * 8;
  const unsigned short* gb2 = Bt + (size_t)(n0 + (c2 >> 2)) * DIM + (c2 & 3) * 8;
  unsigned short* lA1 = &Als[wid * 512];
  unsigned short* lA2 = &Als[2048 + wid * 512];
  unsigned short* lB1 = &Bls[wid * 512];
  unsigned short* lB2 = &Bls[2048 + wid * 512];
  int mb = (wid >> 1) * 64, nb = (wid & 1) * 64;
  int lr = lane & 15, lg = lane >> 4;

  for (int kt = 0; kt < DIM; kt += 32) {
    gload_lds16(ga1 + kt, lA1);
    gload_lds16(ga2 + kt, lA2);
    gload_lds16(gb1 + kt, lB1);
    gload_lds16(gb2 + kt, lB2);
    __syncthreads();
    s8v a[4], b[4];
    #pragma unroll
    for (int i = 0; i < 4; i++) a[i] = *(const s8v*)&Als[(mb + i * 16 + lr) * 32 + lg * 8];
    #pragma unroll
    for (int i = 0; i < 4; i++) b[i] = *(const s8v*)&Bls[(nb + i * 16 + lr) * 32 + lg * 8];
    #pragma unroll
    for (int i = 0; i < 4; i++)
      #pragma unroll
      for (int j = 0; j < 4; j++)
        mfma_bf16(acc[i][j], a[i], b[j]);
    __syncthreads();
  }

  // epilogue: rope on q/k, scatter into frag-major layouts
  #pragma unroll
  for (int i = 0; i < 4; i++) {
    #pragma unroll
    for (int j = 0; j < 4; j++) {
      int colbase = n0 + nb + j * 16;          // wave-uniform
      int type = colbase >> 10;                // 0=q 1=k 2=v
      int hh = (colbase & 1023) >> 6;
      int d0 = colbase & 63;
      int d = d0 + lr;
      int rowt = m0 + mb + i * 16;
      int rowb = rowt + lg * 4;
      f32x4 v = acc[i][j];
      if (type < 2) {
        int p = d >> 1;
        float vr[4];
        #pragma unroll
        for (int r = 0; r < 4; r++) {
          float partner = __shfl_xor(v[r], 1);
          int npos = (rowb + r) & 8191;
          float cth = costab[npos * 32 + p];
          float sth = sintab[npos * 32 + p];
          vr[r] = (d & 1) ? (v[r] * cth + partner * sth)
                          : (v[r] * cth - partner * sth);
        }
        int kk2 = d >> 5, lg2 = (d >> 3) & 3, j2 = d & 7;
        #pragma unroll
        for (int r = 0; r < 4; r++) {
          int m = rowb + r;
          int bw = m >> 9, pos = m & 511;
          int sh2 = bw * 16 + hh;
          unsigned short bits = f2bf(vr[r]);
          if (type == 0)
            q_ws[(size_t)sh2 * 32768 + ((((pos >> 4) * 2 + kk2) * 64) + lg2 * 16 + (pos & 15)) * 8 + j2] = bits;
          else {
            int key = PM + pos;
            k_ws[(size_t)sh2 * 36864 + (key >> 6) * 4096 +
                 (((((key >> 4) & 3) * 2 + kk2) * 64) + lg2 * 16 + (key & 15)) * 8 + j2] = bits;
          }
        }
      } else {
        // V: thread holds (key0..key0+3, d=d0+lr); pack 4 keys -> one 8B store
        int bw = rowb >> 9, sh2 = bw * 16 + hh;
        int key0 = PM + (rowb & 511);
        int chn = key0 >> 6, kk2 = (key0 >> 5) & 1, lg2 = (key0 >> 3) & 3, j0 = key0 & 7;
        int oi2 = d0 >> 4;
        ushort4 pk;
        pk.x = f2bf(v[0]); pk.y = f2bf(v[1]); pk.z = f2bf(v[2]); pk.w = f2bf(v[3]);
        *(ushort4*)&v_ws[(size_t)sh2 * 36864 + chn * 4096 +
                         ((kk2 * 4 + oi2) * 64 + lg2 * 16 + lr) * 8 + j0] = pk;
      }
    }
  }
}

// ---------------- attention (R5 structure, coalesced frag-major loads, no-max softmax) ----------------
__global__ __launch_bounds__(256) void attn_k(const unsigned short* q_ws,
                                              const unsigned short* k_ws,
                                              const unsigned short* v_ws,
                                              unsigned short* attn_out) {
  __shared__ unsigned short Pls[128 * 72];  // per-wave 32 rows
  int bid = blockIdx.x;
  int qt = bid & 3, h = (bid >> 2) & 15, s = bid >> 6;
  int sh = s * 16 + h;
  int tid = threadIdx.x, lane = tid & 63, wid = tid >> 6;
  int lr = lane & 15, lg = lane >> 4;
  int qrow0 = qt * 128 + wid * 32;

  const unsigned short* qsh = q_ws + (size_t)sh * 32768;
  const unsigned short* kbase = k_ws + (size_t)sh * 36864;
  const unsigned short* vbase = v_ws + (size_t)sh * 36864;

  // Q frags: coalesced (lane*16B)
  s8v qf[2][2];
  #pragma unroll
  for (int mi = 0; mi < 2; mi++) {
    int rb = qt * 8 + wid * 2 + mi;
    #pragma unroll
    for (int kk = 0; kk < 2; kk++)
      qf[mi][kk] = *(const s8v*)&qsh[(((rb * 2 + kk) * 64) + lane) * 8];
  }

  f32x4 O[2][4] = {};
  float lrun[2][4] = {};
  int nchunk = 2 * qt + 3;

  for (int cc = 0; cc < nchunk; ++cc) {
    const unsigned short* kch = kbase + cc * 4096;
    const unsigned short* vch = vbase + cc * 4096;
    int kc0 = cc * 64;

    s8v kf[4][2];
    #pragma unroll
    for (int ni = 0; ni < 4; ni++)
      #pragma unroll
      for (int kk = 0; kk < 2; kk++)
        kf[ni][kk] = *(const s8v*)&kch[((ni * 2 + kk) * 64 + lane) * 8];

    f32x4 S[2][4] = {};
    __builtin_amdgcn_s_setprio(1);
    #pragma unroll
    for (int kk = 0; kk < 2; kk++)
      #pragma unroll
      for (int ni = 0; ni < 4; ni++)
        #pragma unroll
        for (int mi = 0; mi < 2; mi++)
          mfma_bf16(S[mi][ni], qf[mi][kk], kf[ni][kk]);
    __builtin_amdgcn_s_setprio(0);

    // V frags issued now; latency hides under softmax
    s8v vf[4][2];
    #pragma unroll
    for (int oi = 0; oi < 4; oi++)
      #pragma unroll
      for (int kk = 0; kk < 2; kk++)
        vf[oi][kk] = *(const s8v*)&vch[((kk * 4 + oi) * 64 + lane) * 8];

    // softmax accumulate (no max tracking; scores bounded, see analysis)
    #pragma unroll
    for (int mi = 0; mi < 2; mi++) {
      bool needmask = (kc0 + 47) > (qrow0 + mi * 16);   // wave-uniform
      if (needmask) {
        #pragma unroll
        for (int r = 0; r < 4; r++) {
          int qpos = qrow0 + mi * 16 + lg * 4 + r;
          float rs = 0.0f;
          #pragma unroll
          for (int ni = 0; ni < 4; ni++) {
            int col = kc0 + ni * 16 + lr;
            bool ok = (col < PM) || ((col - PM) <= qpos);
            float p = ok ? __expf(S[mi][ni][r] * 0.125f) : 0.0f;
            S[mi][ni][r] = p;
            rs += p;
          }
          #pragma unroll
          for (int o = 1; o < 16; o <<= 1) rs += __shfl_xor(rs, o);
          lrun[mi][r] += rs;
        }
      } else {
        #pragma unroll
        for (int r = 0; r < 4; r++) {
          float rs = 0.0f;
          #pragma unroll
          for (int ni = 0; ni < 4; ni++) {
            float p = __expf(S[mi][ni][r] * 0.125f);
            S[mi][ni][r] = p;
            rs += p;
          }
          #pragma unroll
          for (int o = 1; o < 16; o <<= 1) rs += __shfl_xor(rs, o);
          lrun[mi][r] += rs;
        }
      }
    }

    // P -> LDS (R5-proven pattern: scalar ushort writes, s8v reads, wave-private)
    #pragma unroll
    for (int mi = 0; mi < 2; mi++)
      #pragma unroll
      for (int ni = 0; ni < 4; ni++)
        #pragma unroll
        for (int r = 0; r < 4; r++)
          Pls[(wid * 32 + mi * 16 + lg * 4 + r) * 72 + ni * 16 + lr] = f2bf(S[mi][ni][r]);

    __builtin_amdgcn_s_setprio(1);
    #pragma unroll
    for (int kk = 0; kk < 2; kk++) {
      s8v pa[2];
      #pragma unroll
      for (int mi = 0; mi < 2; mi++)
        pa[mi] = *(const s8v*)&Pls[(wid * 32 + mi * 16 + lr) * 72 + kk * 32 + lg * 8];
      #pragma unroll
      for (int oi = 0; oi < 4; oi++)
        #pragma unroll
        for (int mi = 0; mi < 2; mi++)
          mfma_bf16(O[mi][oi], pa[mi], vf[oi][kk]);
    }
    __builtin_amdgcn_s_setprio(0);
    __syncthreads();   // kept from R5 (same ordering guarantees)
  }

  int mbase = (s >> 4) * 8192 + (s & 15) * 512;
  #pragma unroll
  for (int mi = 0; mi < 2; mi++)
    #pragma unroll
    for (int r = 0; r < 4; r++) {
      float inv = 1.0f / lrun[mi][r];
      int qpos = qrow0 + mi * 16 + lg * 4 + r;
      size_t m = (size_t)mbase + qpos;
      #pragma unroll
      for (int oi = 0; oi < 4; oi++)
        attn_out[m * DIM + h * 64 + oi * 16 + lr] = f2bf(O[mi][oi][r] * inv);
    }
}

// ---------------- GEMM 2: out = attn @ WoutT + b ----------------
__global__ __launch_bounds__(256) void gemm_out(const unsigned short* A, const unsigned short* Bt,
                                                const float* bias, float* out) {
  __shared__ unsigned short Als[4096];
  __shared__ unsigned short Bls[4096];
  int tid = threadIdx.x, lane = tid & 63, wid = tid >> 6;
  int n0 = blockIdx.x * 128, m0 = blockIdx.y * 128;
  f32x4 acc[4][4] = {};
  int c2 = tid + 256;
  const unsigned short* ga1 = A + (size_t)(m0 + (tid >> 2)) * DIM + (tid & 3) * 8;
  const unsigned short* ga2 = A + (size_t)(m0 + (c2 >> 2)) * DIM + (c2 & 3) * 8;
  const unsigned short* gb1 = Bt + (size_t)(n0 + (tid >> 2)) * DIM + (tid & 3) * 8;
  const unsigned short* gb2 = Bt + (size_t)(n0 + (c2 >> 2)) * DIM + (c2 & 3) * 8;
  unsigned short* lA1 = &Als[wid * 512];
  unsigned short* lA2 = &Als[2048 + wid * 512];
  unsigned short* lB1 = &Bls[wid * 512];
  unsigned short* lB2 = &Bls[2048 + wid * 512];
  int mb = (wid >> 1) * 64, nb = (wid & 1) * 64;
  int lr = lane & 15, lg = lane >> 4;

  for (int kt = 0; kt < DIM; kt += 32) {
    gload_lds16(ga1 + kt, lA1);
    gload_lds16(ga2 + kt, lA2);
    gload_lds16(gb1 + kt, lB1);
    gload_lds16(gb2 + kt, lB2);
    __syncthreads();
    s8v a[4], b[4];
    #pragma unroll
    for (int i = 0; i < 4; i++) a[i] = *(const s8v*)&Als[(mb + i * 16 + lr) * 32 + lg * 8];
    #pragma unroll
    for (int i = 0; i < 4; i++) b[i] = *(const s8v*)&Bls[(nb + i * 16 + lr) * 32 + lg * 8];
    #pragma unroll
    for (int i = 0; i < 4; i++)
      #pragma unroll
      for (int j = 0; j < 4; j++)
        mfma_bf16(acc[i][j], a[i], b[j]);
    __syncthreads();
  }

  #pragma unroll
  for (int i = 0; i < 4; i++)
    #pragma unroll
    for (int j = 0; j < 4; j++) {
      int c = n0 + nb + j * 16 + lr;
      float bv = bias[c];
      #pragma unroll
      for (int r = 0; r < 4; r++) {
        int m = m0 + mb + i * 16 + lg * 4 + r;
        out[(size_t)m * DIM + c] = acc[i][j][r] + bv;
      }
    }
}

// ---------------- launch ----------------
extern "C" void kernel_launch(void* const* d_in, const int* in_sizes, int n_in,
                              void* d_out, int out_size, void* d_ws, size_t ws_size,
                              hipStream_t stream) {
  (void)in_sizes; (void)n_in; (void)out_size; (void)ws_size;
  const float* seq    = (const float*)d_in[0];
  const float* norm_w = (const float*)d_in[1];
  const float* w_qkv  = (const float*)d_in[2];
  const float* pm_k   = (const float*)d_in[3];
  const float* pm_v   = (const float*)d_in[4];
  const float* w_out  = (const float*)d_in[5];
  const float* b_out  = (const float*)d_in[6];
  float* out = (float*)d_out;

  char* ws = (char*)d_ws;
  unsigned short* xn    = (unsigned short*)(ws);              // 33,554,432 B
  unsigned short* wqkvT = (unsigned short*)(ws + 33554432);   //  6,291,456
  unsigned short* woutT = (unsigned short*)(ws + 39845888);   //  2,097,152
  float* costab         = (float*)(ws + 41943040);            //  1,048,576
  float* sintab         = (float*)(ws + 42991616);            //  1,048,576
  unsigned short* q_ws  = (unsigned short*)(ws + 44040192);   // 33,554,432
  unsigned short* k_ws  = (unsigned short*)(ws + 77594624);   // 37,748,736
  unsigned short* v_ws  = (unsigned short*)(ws + 115343360);  // 37,748,736
  unsigned short* attno = (unsigned short*)(ws + 153092096);  // 33,554,432 (end 186,646,528)

  prep_rope<<<1024, 256, 0, stream>>>(costab, sintab);
  transpose_w<<<dim3(96, 32), dim3(32, 8), 0, stream>>>(w_qkv, wqkvT, 1024, 3072);
  transpose_w<<<dim3(32, 32), dim3(32, 8), 0, stream>>>(w_out, woutT, 1024, 1024);
  prep_pm<<<2048, 256, 0, stream>>>(pm_k, pm_v, k_ws, v_ws);
  clear_vpad<<<6144, 256, 0, stream>>>(v_ws);
  rmsnorm_k<<<16384, 256, 0, stream>>>(seq, norm_w, xn);
  gemm_qkv<<<dim3(24, 128), 256, 0, stream>>>(xn, wqkvT, costab, sintab, q_ws, k_ws, v_ws);
  attn_k<<<2048, 256, 0, stream>>>(q_ws, k_ws, v_ws, attno);
  gemm_out<<<dim3(8, 128), 256, 0, stream>>>(attno, woutT, b_out, out);
}

// Round 7
// 313.628 us; speedup vs baseline: 1.3182x; 1.0751x over previous
//
#include <hip/hip_runtime.h>
#include <stdint.h>

typedef __attribute__((ext_vector_type(8))) short s8v;     // 8 x bf16 bits
typedef __attribute__((ext_vector_type(4))) float f32x4;

#define HEADS 16
#define DH    64
#define SEG   512
#define PM    16
#define NKV   528      // PM + SEG
#define DIM   1024

// frag-major layouts (elements, per sh = seg*16+head):
//  Q: 512x64  -> off = ((rb*2+kk)*64 + lg*16 + lr)*8 + j
//  K: 576x64  -> off = ch*4096 + ((ni*2+kk)*64 + lg*16 + lr)*8 + j
//  V: 576x64  -> off = ch*4096 + ((kk*4+oi)*64 + lg*16 + lr)*8 + j

__device__ __forceinline__ unsigned short f2bf(float f) {
  union { float f; unsigned u; } v; v.f = f;
  unsigned r = v.u + 0x7fffu + ((v.u >> 16) & 1u);
  return (unsigned short)(r >> 16);
}

__device__ __forceinline__ void mfma_bf16(f32x4& c, s8v a, s8v b) {
  asm("v_mfma_f32_16x16x32_bf16 %0, %1, %2, %0" : "+v"(c) : "v"(a), "v"(b));
}

__device__ __forceinline__ void gload_lds16(const unsigned short* g, unsigned short* l) {
  __builtin_amdgcn_global_load_lds(
      (const __attribute__((address_space(1))) unsigned int*)g,
      (__attribute__((address_space(3))) unsigned int*)l, 16, 0, 0);
}

// ---------------- shared 256x256 K-loop (counted-vmcnt 3-buffer pipeline) ----------------
// BM=BN=256, BK=32, 8 waves, per-wave 128x64 (8x4 frags). LDS: 3 bufs x (A 8192 + B 8192)
// elems = 49152 (96KB). Tile t read from buf t%3; tile t+2 staged into buf (t+2)%3 ->
// reader/writer/in-flight bufs distinct mod 3; one raw s_barrier per K-tile; vmcnt(4)
// keeps next tile's 4 loads in flight across the barrier (T4). Row-pair swizzle:
// slot' = ((row&1)*4+lg) ^ ((row>>1)&7), applied on BOTH gload source and ds_read (rule 21).
__device__ __forceinline__ void kloop_256(const unsigned short* Am, const unsigned short* Bm,
                                          int m0, int n0, unsigned short* lds,
                                          f32x4 (&acc)[8][4]) {
  const int tid = threadIdx.x;
  const int w = tid >> 6, lane = tid & 63;
  const int lr = lane & 15, lg = lane >> 4;
  const int wr = w >> 2, wc = w & 3;

  // staging source (pre-swizzled): thread covers line tL, slot S of each 8KB issue
  const int tL = tid >> 3, S = tid & 7;
  const int ls = S ^ (tL & 7);            // logical slot held by this thread's chunk
  const int sub = ls >> 2;                // row within pair
  const int kg = (ls & 3) * 8;            // k-group start
  const unsigned short* asrc = Am + (size_t)(m0 + 2 * tL + sub) * 1024 + kg;
  const unsigned short* bsrc = Bm + (size_t)(n0 + 2 * tL + sub) * 1024 + kg;

  int aoff[8], boff[4];
#pragma unroll
  for (int mf = 0; mf < 8; mf++) {
    int row = wr * 128 + mf * 16 + lr;
    aoff[mf] = (row >> 1) * 64 + (((((row & 1) << 2) | lg) ^ ((row >> 1) & 7)) << 3);
  }
#pragma unroll
  for (int nf = 0; nf < 4; nf++) {
    int col = wc * 64 + nf * 16 + lr;
    boff[nf] = 8192 + (col >> 1) * 64 + (((((col & 1) << 2) | lg) ^ ((col >> 1) & 7)) << 3);
  }

  auto stage = [&](int t) {
    unsigned short* d = lds + (t % 3) * 16384 + w * 512;   // wave-uniform dest
    int kt = t * 32;
    gload_lds16(asrc + kt, d);                     // A rows 0-127
    gload_lds16(asrc + 128 * 1024 + kt, d + 4096); // A rows 128-255
    gload_lds16(bsrc + kt, d + 8192);              // B cols 0-127
    gload_lds16(bsrc + 128 * 1024 + kt, d + 12288);// B cols 128-255
  };

  stage(0);
  stage(1);

  for (int t = 0; t < 32; ++t) {
    if (t < 31) asm volatile("s_waitcnt vmcnt(4)" ::: "memory");  // retire tile t, keep t+1 in flight
    else        asm volatile("s_waitcnt vmcnt(0)" ::: "memory");  // final drain
    __builtin_amdgcn_s_barrier();
    asm volatile("" ::: "memory");   // no memory op crosses the barrier
    if (t + 2 < 32) stage(t + 2);
    const unsigned short* bc = lds + (t % 3) * 16384;
    s8v a[8], bb[4];
#pragma unroll
    for (int mf = 0; mf < 8; mf++) a[mf] = *(const s8v*)&bc[aoff[mf]];
#pragma unroll
    for (int nf = 0; nf < 4; nf++) bb[nf] = *(const s8v*)&bc[boff[nf]];
    __builtin_amdgcn_s_setprio(1);
#pragma unroll
    for (int mf = 0; mf < 8; mf++)
#pragma unroll
      for (int nf = 0; nf < 4; nf++)
        mfma_bf16(acc[mf][nf], a[mf], bb[nf]);
    __builtin_amdgcn_s_setprio(0);
  }
}

// ---------------- prep kernels ----------------
__global__ void prep_rope(float* costab, float* sintab) {
  int idx = blockIdx.x * 256 + threadIdx.x;   // 8192*32
  int n = idx >> 5, p = idx & 31;
  double inv = pow(10000.0, -(double)p / 32.0);
  double ang = (double)n * inv;
  costab[idx] = (float)cos(ang);
  sintab[idx] = (float)sin(ang);
}

__global__ void transpose_w(const float* in, unsigned short* out, int K, int N) {
  // in [K][N] f32 -> out [N][K] bf16
  __shared__ float tile[32][33];
  int n0 = blockIdx.x * 32, k0 = blockIdx.y * 32;
  int tx = threadIdx.x, ty = threadIdx.y;   // (32,8)
  for (int i = ty; i < 32; i += 8) tile[i][tx] = in[(size_t)(k0 + i) * N + n0 + tx];
  __syncthreads();
  for (int i = ty; i < 32; i += 8) out[(size_t)(n0 + i) * K + k0 + tx] = f2bf(tile[tx][i]);
}

__global__ void prep_pm(const float* pm_k, const float* pm_v,
                        unsigned short* k_ws, unsigned short* v_ws) {
  int idx = blockIdx.x * 256 + threadIdx.x;   // 32*16*16*64
  int d = idx & 63, t = (idx >> 6) & 15, h = (idx >> 10) & 15, bw = idx >> 14;
  int sh = bw * 16 + h;
  float kv = pm_k[((h * 16 + t) << 6) + d];
  float vv = pm_v[((h * 16 + t) << 6) + d];
  k_ws[(size_t)sh * 36864 + (((d >> 5) * 64) + ((d >> 3) & 3) * 16 + t) * 8 + (d & 7)] = f2bf(kv);
  v_ws[(size_t)sh * 36864 + (((d >> 4) * 64) + (t >> 3) * 16 + (d & 15)) * 8 + (t & 7)] = f2bf(vv);
}

__global__ void clear_vpad(unsigned short* v_ws) {
  int idx = blockIdx.x * 256 + threadIdx.x;   // 512*64*48
  int t = idx % 48; int rest = idx / 48; int d = rest & 63; int sh = rest >> 6;
  int key = NKV + t;                           // 528..575, ch=8
  int kk = (key >> 5) & 1, lg = (key >> 3) & 3, j = key & 7;
  v_ws[(size_t)sh * 36864 + 8 * 4096 + ((kk * 4 + (d >> 4)) * 64 + lg * 16 + (d & 15)) * 8 + j] = 0;
}

// ---------------- rmsnorm ----------------
__global__ __launch_bounds__(256) void rmsnorm_k(const float* x, const float* w,
                                                 unsigned short* xn) {
  int row = blockIdx.x, tid = threadIdx.x;
  float4 v = ((const float4*)(x + (size_t)row * DIM))[tid];
  float ss = v.x * v.x + v.y * v.y + v.z * v.z + v.w * v.w;
  #pragma unroll
  for (int o = 32; o > 0; o >>= 1) ss += __shfl_xor(ss, o);
  __shared__ float red[4];
  if ((tid & 63) == 0) red[tid >> 6] = ss;
  __syncthreads();
  ss = red[0] + red[1] + red[2] + red[3];
  float rs = rsqrtf(ss * (1.0f / 1024.0f) + 1e-6f);
  float4 wv = ((const float4*)w)[tid];
  ushort4 o;
  o.x = f2bf(v.x * rs * wv.x); o.y = f2bf(v.y * rs * wv.y);
  o.z = f2bf(v.z * rs * wv.z); o.w = f2bf(v.w * rs * wv.w);
  ((ushort4*)(xn + (size_t)row * DIM))[tid] = o;
}

// ---------------- GEMM 1: qkv = xn @ WqkvT, fused rope + frag-major scatter ----------------
__global__ __launch_bounds__(512, 2) void gemm_qkv(const unsigned short* A, const unsigned short* Bt,
                                                   const float* costab, const float* sintab,
                                                   unsigned short* q_ws, unsigned short* k_ws,
                                                   unsigned short* v_ws) {
  __shared__ unsigned short lds[49152];
  int m0 = blockIdx.y * 256, n0 = blockIdx.x * 256;
  f32x4 acc[8][4] = {};
  kloop_256(A, Bt, m0, n0, lds, acc);

  int tid = threadIdx.x, lane = tid & 63, w = tid >> 6;
  int lr = lane & 15, lg = lane >> 4;
  int wr = w >> 2, wc = w & 3;

  // epilogue: rope on q/k, scatter into frag-major layouts
  #pragma unroll
  for (int i = 0; i < 8; i++) {
    #pragma unroll
    for (int j = 0; j < 4; j++) {
      int colbase = n0 + wc * 64 + j * 16;     // wave-uniform
      int type = colbase >> 10;                // 0=q 1=k 2=v (block-uniform: 256 | 1024)
      int hh = (colbase & 1023) >> 6;
      int d0 = colbase & 63;
      int d = d0 + lr;
      int rowt = m0 + wr * 128 + i * 16;
      int rowb = rowt + lg * 4;
      f32x4 v = acc[i][j];
      if (type < 2) {
        int p = d >> 1;
        float vr[4];
        #pragma unroll
        for (int r = 0; r < 4; r++) {
          float partner = __shfl_xor(v[r], 1);
          int npos = (rowb + r) & 8191;
          float cth = costab[npos * 32 + p];
          float sth = sintab[npos * 32 + p];
          vr[r] = (d & 1) ? (v[r] * cth + partner * sth)
                          : (v[r] * cth - partner * sth);
        }
        int kk2 = d >> 5, lg2 = (d >> 3) & 3, j2 = d & 7;
        #pragma unroll
        for (int r = 0; r < 4; r++) {
          int m = rowb + r;
          int bw = m >> 9, pos = m & 511;
          int sh2 = bw * 16 + hh;
          unsigned short bits = f2bf(vr[r]);
          if (type == 0)
            q_ws[(size_t)sh2 * 32768 + ((((pos >> 4) * 2 + kk2) * 64) + lg2 * 16 + (pos & 15)) * 8 + j2] = bits;
          else {
            int key = PM + pos;
            k_ws[(size_t)sh2 * 36864 + (key >> 6) * 4096 +
                 (((((key >> 4) & 3) * 2 + kk2) * 64) + lg2 * 16 + (key & 15)) * 8 + j2] = bits;
          }
        }
      } else {
        // V: thread holds (key0..key0+3, d=d0+lr); pack 4 keys -> one 8B store
        int bw = rowb >> 9, sh2 = bw * 16 + hh;
        int key0 = PM + (rowb & 511);
        int chn = key0 >> 6, kk2 = (key0 >> 5) & 1, lg2 = (key0 >> 3) & 3, j0 = key0 & 7;
        int oi2 = d0 >> 4;
        ushort4 pk;
        pk.x = f2bf(v[0]); pk.y = f2bf(v[1]); pk.z = f2bf(v[2]); pk.w = f2bf(v[3]);
        *(ushort4*)&v_ws[(size_t)sh2 * 36864 + chn * 4096 +
                         ((kk2 * 4 + oi2) * 64 + lg2 * 16 + lr) * 8 + j0] = pk;
      }
    }
  }
}

// ---------------- attention (R6-proven: coalesced frag-major loads, no-max softmax) ----------------
__global__ __launch_bounds__(256) void attn_k(const unsigned short* q_ws,
                                              const unsigned short* k_ws,
                                              const unsigned short* v_ws,
                                              unsigned short* attn_out) {
  __shared__ unsigned short Pls[128 * 72];  // per-wave 32 rows
  int bid = blockIdx.x;
  int qt = bid & 3, h = (bid >> 2) & 15, s = bid >> 6;
  int sh = s * 16 + h;
  int tid = threadIdx.x, lane = tid & 63, wid = tid >> 6;
  int lr = lane & 15, lg = lane >> 4;
  int qrow0 = qt * 128 + wid * 32;

  const unsigned short* qsh = q_ws + (size_t)sh * 32768;
  const unsigned short* kbase = k_ws + (size_t)sh * 36864;
  const unsigned short* vbase = v_ws + (size_t)sh * 36864;

  s8v qf[2][2];
  #pragma unroll
  for (int mi = 0; mi < 2; mi++) {
    int rb = qt * 8 + wid * 2 + mi;
    #pragma unroll
    for (int kk = 0; kk < 2; kk++)
      qf[mi][kk] = *(const s8v*)&qsh[(((rb * 2 + kk) * 64) + lane) * 8];
  }

  f32x4 O[2][4] = {};
  float lrun[2][4] = {};
  int nchunk = 2 * qt + 3;

  for (int cc = 0; cc < nchunk; ++cc) {
    const unsigned short* kch = kbase + cc * 4096;
    const unsigned short* vch = vbase + cc * 4096;
    int kc0 = cc * 64;

    s8v kf[4][2];
    #pragma unroll
    for (int ni = 0; ni < 4; ni++)
      #pragma unroll
      for (int kk = 0; kk < 2; kk++)
        kf[ni][kk] = *(const s8v*)&kch[((ni * 2 + kk) * 64 + lane) * 8];

    f32x4 S[2][4] = {};
    __builtin_amdgcn_s_setprio(1);
    #pragma unroll
    for (int kk = 0; kk < 2; kk++)
      #pragma unroll
      for (int ni = 0; ni < 4; ni++)
        #pragma unroll
        for (int mi = 0; mi < 2; mi++)
          mfma_bf16(S[mi][ni], qf[mi][kk], kf[ni][kk]);
    __builtin_amdgcn_s_setprio(0);

    s8v vf[4][2];
    #pragma unroll
    for (int oi = 0; oi < 4; oi++)
      #pragma unroll
      for (int kk = 0; kk < 2; kk++)
        vf[oi][kk] = *(const s8v*)&vch[((kk * 4 + oi) * 64 + lane) * 8];

    #pragma unroll
    for (int mi = 0; mi < 2; mi++) {
      bool needmask = (kc0 + 47) > (qrow0 + mi * 16);   // wave-uniform
      if (needmask) {
        #pragma unroll
        for (int r = 0; r < 4; r++) {
          int qpos = qrow0 + mi * 16 + lg * 4 + r;
          float rs = 0.0f;
          #pragma unroll
          for (int ni = 0; ni < 4; ni++) {
            int col = kc0 + ni * 16 + lr;
            bool ok = (col < PM) || ((col - PM) <= qpos);
            float p = ok ? __expf(S[mi][ni][r] * 0.125f) : 0.0f;
            S[mi][ni][r] = p;
            rs += p;
          }
          #pragma unroll
          for (int o = 1; o < 16; o <<= 1) rs += __shfl_xor(rs, o);
          lrun[mi][r] += rs;
        }
      } else {
        #pragma unroll
        for (int r = 0; r < 4; r++) {
          float rs = 0.0f;
          #pragma unroll
          for (int ni = 0; ni < 4; ni++) {
            float p = __expf(S[mi][ni][r] * 0.125f);
            S[mi][ni][r] = p;
            rs += p;
          }
          #pragma unroll
          for (int o = 1; o < 16; o <<= 1) rs += __shfl_xor(rs, o);
          lrun[mi][r] += rs;
        }
      }
    }

    #pragma unroll
    for (int mi = 0; mi < 2; mi++)
      #pragma unroll
      for (int ni = 0; ni < 4; ni++)
        #pragma unroll
        for (int r = 0; r < 4; r++)
          Pls[(wid * 32 + mi * 16 + lg * 4 + r) * 72 + ni * 16 + lr] = f2bf(S[mi][ni][r]);

    __builtin_amdgcn_s_setprio(1);
    #pragma unroll
    for (int kk = 0; kk < 2; kk++) {
      s8v pa[2];
      #pragma unroll
      for (int mi = 0; mi < 2; mi++)
        pa[mi] = *(const s8v*)&Pls[(wid * 32 + mi * 16 + lr) * 72 + kk * 32 + lg * 8];
      #pragma unroll
      for (int oi = 0; oi < 4; oi++)
        #pragma unroll
        for (int mi = 0; mi < 2; mi++)
          mfma_bf16(O[mi][oi], pa[mi], vf[oi][kk]);
    }
    __builtin_amdgcn_s_setprio(0);
    __syncthreads();
  }

  int mbase = (s >> 4) * 8192 + (s & 15) * 512;
  #pragma unroll
  for (int mi = 0; mi < 2; mi++)
    #pragma unroll
    for (int r = 0; r < 4; r++) {
      float inv = 1.0f / lrun[mi][r];
      int qpos = qrow0 + mi * 16 + lg * 4 + r;
      size_t m = (size_t)mbase + qpos;
      #pragma unroll
      for (int oi = 0; oi < 4; oi++)
        attn_out[m * DIM + h * 64 + oi * 16 + lr] = f2bf(O[mi][oi][r] * inv);
    }
}

// ---------------- GEMM 2: out = attn @ WoutT + b ----------------
__global__ __launch_bounds__(512, 2) void gemm_out(const unsigned short* A, const unsigned short* Bt,
                                                   const float* bias, float* out) {
  __shared__ unsigned short lds[49152];
  int m0 = blockIdx.y * 256, n0 = blockIdx.x * 256;
  f32x4 acc[8][4] = {};
  kloop_256(A, Bt, m0, n0, lds, acc);

  int tid = threadIdx.x, lane = tid & 63, w = tid >> 6;
  int lr = lane & 15, lg = lane >> 4;
  int wr = w >> 2, wc = w & 3;

  #pragma unroll
  for (int i = 0; i < 8; i++)
    #pragma unroll
    for (int j = 0; j < 4; j++) {
      int c = n0 + wc * 64 + j * 16 + lr;
      float bv = bias[c];
      #pragma unroll
      for (int r = 0; r < 4; r++) {
        int m = m0 + wr * 128 + i * 16 + lg * 4 + r;
        out[(size_t)m * DIM + c] = acc[i][j][r] + bv;
      }
    }
}

// ---------------- launch ----------------
extern "C" void kernel_launch(void* const* d_in, const int* in_sizes, int n_in,
                              void* d_out, int out_size, void* d_ws, size_t ws_size,
                              hipStream_t stream) {
  (void)in_sizes; (void)n_in; (void)out_size; (void)ws_size;
  const float* seq    = (const float*)d_in[0];
  const float* norm_w = (const float*)d_in[1];
  const float* w_qkv  = (const float*)d_in[2];
  const float* pm_k   = (const float*)d_in[3];
  const float* pm_v   = (const float*)d_in[4];
  const float* w_out  = (const float*)d_in[5];
  const float* b_out  = (const float*)d_in[6];
  float* out = (float*)d_out;

  char* ws = (char*)d_ws;
  unsigned short* xn    = (unsigned short*)(ws);              // 33,554,432 B
  unsigned short* wqkvT = (unsigned short*)(ws + 33554432);   //  6,291,456
  unsigned short* woutT = (unsigned short*)(ws + 39845888);   //  2,097,152
  float* costab         = (float*)(ws + 41943040);            //  1,048,576
  float* sintab         = (float*)(ws + 42991616);            //  1,048,576
  unsigned short* q_ws  = (unsigned short*)(ws + 44040192);   // 33,554,432
  unsigned short* k_ws  = (unsigned short*)(ws + 77594624);   // 37,748,736
  unsigned short* v_ws  = (unsigned short*)(ws + 115343360);  // 37,748,736
  unsigned short* attno = (unsigned short*)(ws + 153092096);  // 33,554,432 (end 186,646,528)

  prep_rope<<<1024, 256, 0, stream>>>(costab, sintab);
  transpose_w<<<dim3(96, 32), dim3(32, 8), 0, stream>>>(w_qkv, wqkvT, 1024, 3072);
  transpose_w<<<dim3(32, 32), dim3(32, 8), 0, stream>>>(w_out, woutT, 1024, 1024);
  prep_pm<<<2048, 256, 0, stream>>>(pm_k, pm_v, k_ws, v_ws);
  clear_vpad<<<6144, 256, 0, stream>>>(v_ws);
  rmsnorm_k<<<16384, 256, 0, stream>>>(seq, norm_w, xn);
  gemm_qkv<<<dim3(12, 64), 512, 0, stream>>>(xn, wqkvT, costab, sintab, q_ws, k_ws, v_ws);
  attn_k<<<2048, 256, 0, stream>>>(q_ws, k_ws, v_ws, attno);
  gemm_out<<<dim3(4, 64), 512, 0, stream>>>(attno, woutT, b_out, out);
}